// Round 6
// baseline (285.099 us; speedup 1.0000x reference)
//
#include <hip/hip_runtime.h>
#include <hip/hip_bf16.h>

typedef _Float16 half8 __attribute__((ext_vector_type(8)));
typedef _Float16 half4v __attribute__((ext_vector_type(4)));
typedef float f32x4 __attribute__((ext_vector_type(4)));

#define SWZ(byte, r) ((unsigned)(byte) ^ ((((unsigned)(r)) & 7u) << 4))

constexpr int Bb = 128;     // batches
constexpr int Nn = 2048;    // nodes
constexpr int Ee = 128;     // embed
constexpr int BM1 = 128;    // rows per tile in persistent GEMM passes
constexpr int P1_BLOCKS = 256;
constexpr int P1_ITERS = (Bb * Nn) / BM1 / P1_BLOCKS;   // 8

// workspace layout (bytes)
constexpr size_t OFF_W    = 0;                                   // 4 tiles x 32768 (f16, pre-swizzled)
constexpr size_t OFF_PROJ = 131072;                              // [B*N][128] f16, pre-swizzled, 64 MiB
constexpr size_t OFF_UT   = OFF_PROJ + (size_t)Bb * Nn * Ee * 2; // [B*N] f32
constexpr size_t OFF_UT2  = OFF_UT   + (size_t)Bb * Nn * 4;
constexpr size_t OFF_HP   = OFF_UT2  + (size_t)Bb * Nn * 4;      // [B][16][128] f32 partial h_i

// async global->LDS copy, 16 B per lane (wave-uniform dest base + lane*16)
__device__ __forceinline__ void cp16(void* lds, const void* g) {
    __builtin_amdgcn_global_load_lds(
        (const __attribute__((address_space(1))) unsigned int*)g,
        (__attribute__((address_space(3))) unsigned int*)lds, 16, 0, 0);
}

__device__ __forceinline__ float fast_tanh(float x) {
    float e = __expf(2.0f * x);
    return 1.0f - 2.0f * __builtin_amdgcn_rcpf(e + 1.0f);
}

// ---------------- prep: convert weights fp32 -> f16, pre-swizzled tiles ----------------
// tile 0: W_s, tile 1: W_a, tile 2: W_c1=W_c[:, :128], tile 3: W_c2=W_c[:, 128:]
__global__ __launch_bounds__(256) void k_prep(const float* __restrict__ Ws,
                                              const float* __restrict__ Wa,
                                              const float* __restrict__ Wc,
                                              char* __restrict__ wdst)
{
    int id = blockIdx.x * 256 + threadIdx.x;
    for (int i = id; i < 65536; i += 64 * 256) {
        int mat = i >> 14;
        int rem = i & 16383;
        int r = rem >> 7, c = rem & 127;
        float v;
        if      (mat == 0) v = Ws[r * 128 + c];
        else if (mat == 1) v = Wa[r * 128 + c];
        else if (mat == 2) v = Wc[r * 256 + c];
        else               v = Wc[r * 256 + 128 + c];
        unsigned off = SWZ((unsigned)((r * 128 + c) * 2), r);
        *reinterpret_cast<_Float16*>(wdst + (size_t)mat * 32768 + off) = (_Float16)v;
    }
}

// ---------------- pass1 (persistent): proj + u_t ----------------------------------------
__global__ __launch_bounds__(512) void k_pass1(const float* __restrict__ inst,
                                               const char* __restrict__ wtiles,
                                               const float* __restrict__ bs,
                                               const float* __restrict__ ba,
                                               const float* __restrict__ va,
                                               char* __restrict__ projg,
                                               float* __restrict__ ut)
{
    __shared__ _Float16 ldsW[2 * 16384];   // 64 KB: W_s | W_a (pre-swizzled)
    __shared__ _Float16 bufA[2][16384];    // 2 x 32 KB double-buffered row tiles

    const int tid  = threadIdx.x;
    const int lane = tid & 63;
    const int w    = tid >> 6;        // 8 waves
    const int l15  = lane & 15;
    const int kg   = lane >> 4;
    const int arow = w * 16 + l15;    // covers 128 rows

    // stage W_s + W_a (64 KB) async, once
    #pragma unroll
    for (int i = 0; i < 8; ++i) {
        unsigned o = (unsigned)((i * 512 + tid) * 16);
        cp16((char*)ldsW + o, wtiles + o);
    }

    const size_t tile0 = (size_t)blockIdx.x * P1_ITERS;
    float4 v[8];
    {   // load tile 0 fp32 into regs
        const float* src = inst + tile0 * BM1 * 128;
        #pragma unroll
        for (int i = 0; i < 8; ++i)
            v[i] = *reinterpret_cast<const float4*>(src + (size_t)(i * 512 + tid) * 4);
    }
    // convert tile 0 into bufA[0] (swizzled f16)
    #pragma unroll
    for (int i = 0; i < 8; ++i) {
        int f = i * 512 + tid;
        int r = f >> 5, c4 = f & 31;
        half4v h = { (_Float16)v[i].x, (_Float16)v[i].y, (_Float16)v[i].z, (_Float16)v[i].w };
        *reinterpret_cast<half4v*>((char*)bufA[0] + SWZ(r * 256 + c4 * 8, r)) = h;
    }
    __syncthreads();   // weights + buf0 ready

    for (int it = 0; it < P1_ITERS; ++it) {
        const int cur = it & 1, nxt = cur ^ 1;
        const size_t row0 = (tile0 + it) * BM1;

        // issue next-tile fp32 loads early (hide HBM latency under GEMM1)
        if (it + 1 < P1_ITERS) {
            const float* src = inst + (row0 + BM1) * 128;
            #pragma unroll
            for (int i = 0; i < 8; ++i)
                v[i] = *reinterpret_cast<const float4*>(src + (size_t)(i * 512 + tid) * 4);
        }

        // GEMM1: proj = inst @ Ws^T
        f32x4 acc[8];
        #pragma unroll
        for (int fr = 0; fr < 8; ++fr) acc[fr] = f32x4{0.f, 0.f, 0.f, 0.f};
        #pragma unroll
        for (int kk = 0; kk < 4; ++kk) {
            half8 af = *reinterpret_cast<const half8*>(
                (char*)bufA[cur] + SWZ(arow * 256 + kk * 64 + kg * 16, arow));
            #pragma unroll
            for (int fr = 0; fr < 8; ++fr) {
                int br = fr * 16 + l15;
                half8 bf = *reinterpret_cast<const half8*>(
                    (char*)ldsW + SWZ(br * 256 + kk * 64 + kg * 16, br));
                acc[fr] = __builtin_amdgcn_mfma_f32_16x16x32_f16(af, bf, acc[fr], 0, 0, 0);
            }
        }
        __syncthreads();   // GEMM1 LDS reads complete

        // proj(+bias) overwrites bufA[cur]
        #pragma unroll
        for (int fr = 0; fr < 8; ++fr) {
            int e = fr * 16 + l15;
            float bsv = bs[e];
            #pragma unroll
            for (int j = 0; j < 4; ++j) {
                int r = w * 16 + kg * 4 + j;
                *reinterpret_cast<_Float16*>((char*)bufA[cur] + SWZ(r * 256 + e * 2, r)) =
                    (_Float16)(acc[fr][j] + bsv);
            }
        }
        // convert next inst tile -> bufA[nxt]
        if (it + 1 < P1_ITERS) {
            #pragma unroll
            for (int i = 0; i < 8; ++i) {
                int f = i * 512 + tid;
                int r = f >> 5, c4 = f & 31;
                half4v h = { (_Float16)v[i].x, (_Float16)v[i].y, (_Float16)v[i].z, (_Float16)v[i].w };
                *reinterpret_cast<half4v*>((char*)bufA[nxt] + SWZ(r * 256 + c4 * 8, r)) = h;
            }
        }
        __syncthreads();   // proj + next tile ready

        // GEMM2: tac = proj @ Wa^T   (W_a at ldsW + 32768)
        f32x4 tac[8];
        #pragma unroll
        for (int fr = 0; fr < 8; ++fr) tac[fr] = f32x4{0.f, 0.f, 0.f, 0.f};
        #pragma unroll
        for (int kk = 0; kk < 4; ++kk) {
            half8 af = *reinterpret_cast<const half8*>(
                (char*)bufA[cur] + SWZ(arow * 256 + kk * 64 + kg * 16, arow));
            #pragma unroll
            for (int fr = 0; fr < 8; ++fr) {
                int br = fr * 16 + l15;
                half8 bf = *reinterpret_cast<const half8*>(
                    (char*)ldsW + 32768 + SWZ(br * 256 + kk * 64 + kg * 16, br));
                tac[fr] = __builtin_amdgcn_mfma_f32_16x16x32_f16(af, bf, tac[fr], 0, 0, 0);
            }
        }

        // copy proj tile (pre-swizzled) -> global
        {
            char* dst = projg + row0 * 256;
            #pragma unroll
            for (int i = 0; i < 4; ++i) {
                unsigned o = (unsigned)((i * 512 + tid) * 16);
                *reinterpret_cast<uint4*>(dst + o) =
                    *reinterpret_cast<const uint4*>((const char*)bufA[cur] + o);
            }
        }

        // epilogue: u_t = v_a . tanh(tac + ba)
        float u[4] = {0.f, 0.f, 0.f, 0.f};
        #pragma unroll
        for (int fr = 0; fr < 8; ++fr) {
            int fcol = fr * 16 + l15;
            float vav = va[fcol], bav = ba[fcol];
            #pragma unroll
            for (int j = 0; j < 4; ++j)
                u[j] += vav * fast_tanh(tac[fr][j] + bav);
        }
        #pragma unroll
        for (int d = 1; d < 16; d <<= 1) {
            #pragma unroll
            for (int j = 0; j < 4; ++j) u[j] += __shfl_xor(u[j], d);
        }
        if (l15 == 0) {
            #pragma unroll
            for (int j = 0; j < 4; ++j)
                ut[row0 + w * 16 + kg * 4 + j] = u[j];
        }
    }
}

// ---------------- pass2 (persistent, fused a_t softmax): u_t_2 --------------------------
// 2 blocks per batch; each block recomputes softmax(u_t[batch]) redundantly, then
// streams 8 proj tiles of 128 rows with single-barrier DMA pipeline.
__global__ __launch_bounds__(512) void k_pass2(const char* __restrict__ projg,
                                               const char* __restrict__ wtiles,
                                               const float* __restrict__ bc,
                                               const float* __restrict__ vc,
                                               const float* __restrict__ ut,
                                               float* __restrict__ ut2)
{
    __shared__ _Float16 ldsW[2 * 16384];   // 64 KB: W_c1 | W_c2
    __shared__ _Float16 bufP[2][16384];    // 2 x 32 KB proj tiles
    __shared__ float at_lds[1024];
    __shared__ float redm[8], reds[8];

    const int tid  = threadIdx.x;
    const int lane = tid & 63;
    const int w    = tid >> 6;
    const int l15  = lane & 15;
    const int kg   = lane >> 4;
    const int arow = w * 16 + l15;
    const int bid  = blockIdx.x;
    const int batch = bid >> 1, half = bid & 1;

    // softmax(u_t[batch]) — redundant per block, 8 KB read
    const float* utb = ut + (size_t)batch * Nn;
    float4 x = *reinterpret_cast<const float4*>(utb + tid * 4);
    float m = fmaxf(fmaxf(x.x, x.y), fmaxf(x.z, x.w));
    #pragma unroll
    for (int d = 1; d < 64; d <<= 1) m = fmaxf(m, __shfl_xor(m, d));
    if (lane == 0) redm[w] = m;
    __syncthreads();
    float M = redm[0];
    #pragma unroll
    for (int k = 1; k < 8; ++k) M = fmaxf(M, redm[k]);
    float e0 = __expf(x.x - M), e1 = __expf(x.y - M), e2 = __expf(x.z - M), e3 = __expf(x.w - M);
    float s = e0 + e1 + e2 + e3;
    #pragma unroll
    for (int d = 1; d < 64; d <<= 1) s += __shfl_xor(s, d);
    if (lane == 0) reds[w] = s;
    __syncthreads();
    float S = 0.f;
    #pragma unroll
    for (int k = 0; k < 8; ++k) S += reds[k];
    float invS = 1.0f / S;

    // stage weights (64 KB, once) + proj tile 0 async
    #pragma unroll
    for (int i = 0; i < 8; ++i) {
        unsigned o = (unsigned)((i * 512 + tid) * 16);
        cp16((char*)ldsW + o, wtiles + 65536 + o);
    }
    const char* psrc = projg + ((size_t)batch * Nn + (size_t)half * 1024) * 256;
    #pragma unroll
    for (int i = 0; i < 4; ++i) {
        unsigned o = (unsigned)((i * 512 + tid) * 16);
        cp16((char*)bufP[0] + o, psrc + o);
    }
    // a_t table for this block's 1024 rows (threads holding this half's u_t values)
    if ((tid >> 8) == half) {
        int rl = (tid & 255) * 4;
        at_lds[rl + 0] = e0 * invS;
        at_lds[rl + 1] = e1 * invS;
        at_lds[rl + 2] = e2 * invS;
        at_lds[rl + 3] = e3 * invS;
    }

    for (int it = 0; it < 8; ++it) {
        const int cur = it & 1, nxt = cur ^ 1;
        __syncthreads();   // drains prefetch: bufP[cur] + (it==0: weights + at_lds)

        if (it + 1 < 8) {  // prefetch next tile, stays in flight through GEMMs
            #pragma unroll
            for (int i = 0; i < 4; ++i) {
                unsigned o = (unsigned)((i * 512 + tid) * 16);
                cp16((char*)bufP[nxt] + o, psrc + (size_t)(it + 1) * 32768 + o);
            }
        }

        f32x4 u1[8], u2[8];
        #pragma unroll
        for (int fr = 0; fr < 8; ++fr) { u1[fr] = f32x4{0.f,0.f,0.f,0.f}; u2[fr] = f32x4{0.f,0.f,0.f,0.f}; }
        #pragma unroll
        for (int kk = 0; kk < 4; ++kk) {
            half8 af = *reinterpret_cast<const half8*>(
                (char*)bufP[cur] + SWZ(arow * 256 + kk * 64 + kg * 16, arow));
            #pragma unroll
            for (int fr = 0; fr < 8; ++fr) {
                int br = fr * 16 + l15;
                half8 bf1 = *reinterpret_cast<const half8*>(
                    (char*)ldsW + SWZ(br * 256 + kk * 64 + kg * 16, br));
                u1[fr] = __builtin_amdgcn_mfma_f32_16x16x32_f16(af, bf1, u1[fr], 0, 0, 0);
                half8 bf2 = *reinterpret_cast<const half8*>(
                    (char*)ldsW + 32768 + SWZ(br * 256 + kk * 64 + kg * 16, br));
                u2[fr] = __builtin_amdgcn_mfma_f32_16x16x32_f16(af, bf2, u2[fr], 0, 0, 0);
            }
        }

        float aj[4];
        #pragma unroll
        for (int j = 0; j < 4; ++j) aj[j] = at_lds[it * 128 + w * 16 + kg * 4 + j];
        float u[4] = {0.f, 0.f, 0.f, 0.f};
        #pragma unroll
        for (int fr = 0; fr < 8; ++fr) {
            int fcol = fr * 16 + l15;
            float vcv = vc[fcol], bcv = bc[fcol];
            #pragma unroll
            for (int j = 0; j < 4; ++j)
                u[j] += vcv * fast_tanh(u1[fr][j] + aj[j] * u2[fr][j] + bcv);
        }
        #pragma unroll
        for (int d = 1; d < 16; d <<= 1) {
            #pragma unroll
            for (int j = 0; j < 4; ++j) u[j] += __shfl_xor(u[j], d);
        }
        if (l15 == 0) {
            #pragma unroll
            for (int j = 0; j < 4; ++j)
                ut2[(size_t)batch * Nn + (size_t)half * 1024 + it * 128 + w * 16 + kg * 4 + j] = u[j];
        }
    }
}

// ---------------- k_hi: fused softmax(prob) + partial h_i -------------------------------
__global__ __launch_bounds__(256) void k_hi(const float* __restrict__ ut2,
                                            const char* __restrict__ projg,
                                            float* __restrict__ hpart)
{
    __shared__ float pw[128];
    __shared__ float hp[16][128];
    __shared__ float redm[4], reds[4];

    const int bid = blockIdx.x;
    const int b = bid >> 4, chunk = bid & 15;
    const int n0 = chunk * 128;
    const int tid = threadIdx.x;
    const int lane = tid & 63, w = tid >> 6;

    // softmax(u_t_2[b]) — redundant per block
    const float* u2b = ut2 + (size_t)b * Nn;
    float4 x0 = *reinterpret_cast<const float4*>(u2b + tid * 8);
    float4 x1 = *reinterpret_cast<const float4*>(u2b + tid * 8 + 4);
    float m = fmaxf(fmaxf(fmaxf(x0.x, x0.y), fmaxf(x0.z, x0.w)),
                    fmaxf(fmaxf(x1.x, x1.y), fmaxf(x1.z, x1.w)));
    #pragma unroll
    for (int d = 1; d < 64; d <<= 1) m = fmaxf(m, __shfl_xor(m, d));
    if (lane == 0) redm[w] = m;
    __syncthreads();
    float M = fmaxf(fmaxf(redm[0], redm[1]), fmaxf(redm[2], redm[3]));
    float e[8] = { __expf(x0.x - M), __expf(x0.y - M), __expf(x0.z - M), __expf(x0.w - M),
                   __expf(x1.x - M), __expf(x1.y - M), __expf(x1.z - M), __expf(x1.w - M) };
    float s = 0.f;
    #pragma unroll
    for (int i = 0; i < 8; ++i) s += e[i];
    #pragma unroll
    for (int d = 1; d < 64; d <<= 1) s += __shfl_xor(s, d);
    if (lane == 0) reds[w] = s;
    __syncthreads();
    float inv = 1.0f / (reds[0] + reds[1] + reds[2] + reds[3]);
    // this block's 128 probs (threads tid>>4==chunk hold them: tid*8 in [n0, n0+128))
    if ((tid >> 4) == chunk) {
        int base = (tid & 15) * 8;
        #pragma unroll
        for (int k = 0; k < 8; ++k) pw[base + k] = e[k] * inv;
    }
    __syncthreads();

    const int rg = tid >> 4, c16 = tid & 15;
    const char* pb = projg + ((size_t)b * Nn + n0) * 256;
    float acc[8] = {0.f,0.f,0.f,0.f,0.f,0.f,0.f,0.f};
    #pragma unroll
    for (int itn = 0; itn < 8; ++itn) {
        int nl = rg + itn * 16;
        float wgt = pw[nl];
        unsigned off = (unsigned)(nl * 256 + ((c16 * 16) ^ ((nl & 7) << 4)));
        half8 ph = *reinterpret_cast<const half8*>(pb + off);
        #pragma unroll
        for (int j = 0; j < 8; ++j) acc[j] += wgt * (float)ph[j];
    }
    #pragma unroll
    for (int j = 0; j < 8; ++j) hp[rg][c16 * 8 + j] = acc[j];
    __syncthreads();
    if (tid < 128) {
        float s2 = 0.f;
        #pragma unroll
        for (int k = 0; k < 16; ++k) s2 += hp[k][tid];
        hpart[((size_t)b * 16 + chunk) * 128 + tid] = s2;
    }
}

// ---------------- k_head: h_i reduce + MLP head -----------------------------------------
__global__ __launch_bounds__(128) void k_head(const float* __restrict__ hpart,
                                              const float* __restrict__ W1,
                                              const float* __restrict__ b1,
                                              const float* __restrict__ W2,
                                              const float* __restrict__ b2,
                                              float* __restrict__ out)
{
    __shared__ float h[128];
    __shared__ float o1[128];
    const int b = blockIdx.x, tid = threadIdx.x;

    float s = 0.f;
    #pragma unroll
    for (int c = 0; c < 16; ++c) s += hpart[((size_t)b * 16 + c) * 128 + tid];
    h[tid] = s;
    __syncthreads();

    const float* wr = W1 + tid * 128;
    float o = b1[tid];
    #pragma unroll 8
    for (int e = 0; e < 128; e += 4) {
        float4 wv = *reinterpret_cast<const float4*>(wr + e);
        o += wv.x * h[e] + wv.y * h[e+1] + wv.z * h[e+2] + wv.w * h[e+3];
    }
    o1[tid] = fmaxf(o, 0.f);
    __syncthreads();

    if (tid < 64) {
        float p = o1[tid] * W2[tid] + o1[tid + 64] * W2[tid + 64];
        #pragma unroll
        for (int d = 1; d < 64; d <<= 1) p += __shfl_xor(p, d);
        if (tid == 0) out[b] = p + b2[0];
    }
}

// ---------------------------------------------------------------------------------------
extern "C" void kernel_launch(void* const* d_in, const int* in_sizes, int n_in,
                              void* d_out, int out_size, void* d_ws, size_t ws_size,
                              hipStream_t stream)
{
    const float* inst = (const float*)d_in[0];
    const float* Ws   = (const float*)d_in[1];
    const float* bs   = (const float*)d_in[2];
    const float* Wa   = (const float*)d_in[3];
    const float* ba   = (const float*)d_in[4];
    const float* va   = (const float*)d_in[5];
    const float* Wc   = (const float*)d_in[6];
    const float* bc   = (const float*)d_in[7];
    const float* vc   = (const float*)d_in[8];
    const float* W1   = (const float*)d_in[9];
    const float* b1   = (const float*)d_in[10];
    const float* W2   = (const float*)d_in[11];
    const float* b2   = (const float*)d_in[12];
    float* out = (float*)d_out;

    char*  ws     = (char*)d_ws;
    char*  wtiles = ws + OFF_W;
    char*  projg  = ws + OFF_PROJ;
    float* ut     = (float*)(ws + OFF_UT);
    float* ut2    = (float*)(ws + OFF_UT2);
    float* hpart  = (float*)(ws + OFF_HP);

    hipLaunchKernelGGL(k_prep,  dim3(64),        dim3(256), 0, stream, Ws, Wa, Wc, wtiles);
    hipLaunchKernelGGL(k_pass1, dim3(P1_BLOCKS), dim3(512), 0, stream, inst, wtiles, bs, ba, va, projg, ut);
    hipLaunchKernelGGL(k_pass2, dim3(Bb * 2),    dim3(512), 0, stream, projg, wtiles, bc, vc, ut, ut2);
    hipLaunchKernelGGL(k_hi,    dim3(Bb * 16),   dim3(256), 0, stream, ut2, projg, hpart);
    hipLaunchKernelGGL(k_head,  dim3(Bb),        dim3(128), 0, stream, hpart, W1, b1, W2, b2, out);
}